// Round 8
// baseline (308.899 us; speedup 1.0000x reference)
//
#include <hip/hip_runtime.h>

typedef __bf16 bf16_t;
typedef __bf16 bf16x4_t __attribute__((ext_vector_type(4)));
typedef __bf16 bf16x8 __attribute__((ext_vector_type(8)));
typedef float f32x4 __attribute__((ext_vector_type(4)));

#define NH 8
#define DH 32
#define QL 256
#define KL 256
#define CIN 64
#define HD 256  // NH*DH

__device__ __forceinline__ bf16_t f2bf(float x) { return (bf16_t)x; }

__device__ __forceinline__ f32x4 mfma16(bf16x8 a, bf16x8 b, f32x4 c) {
    return __builtin_amdgcn_mfma_f32_16x16x32_bf16(a, b, c, 0, 0, 0);
}

__device__ __forceinline__ bf16x8 cvt8(const float* __restrict__ p) {
    const f32x4 lo = *(const f32x4*)p;
    const f32x4 hi = *(const f32x4*)(p + 4);
    bf16x8 r;
#pragma unroll
    for (int j = 0; j < 4; ++j) { r[j] = f2bf(lo[j]); r[4 + j] = f2bf(hi[j]); }
    return r;
}

// ---------------------------------------------------------------------------
// Phase 1 v2: high-TLP projection. Flat grid 3072 = (s, h, which) with XCD
// swizzle: b&7 selects a 16-s band -> per-XCD X working set ~2 MB (L2-resident,
// r6/r7 lesson). Each block stages only its 8 KB W head-slice (15 KB LDS ->
// 6 blocks/CU). 8 special blocks (which==1, s==0) also emit Wo fragment-native.
//   Qf/Kf per (s,h): 16 tiles x [lane][8], elem = M[tile*16+l16][quad*8+j]
//   Vf  per (s,h): 16 chunks x [lane][8],  elem = V[cs*32+quad*8+j][nt*16+l16]
//   WoF: (h*4+nt) x [lane][8], elem = Wo[h*32+quad*8+j][nt*16+l16]
__launch_bounds__(256, 6)
__global__ void proj_v2(const float* __restrict__ Xq, const float* __restrict__ Xkv,
                        const float* __restrict__ Wq, const float* __restrict__ Wk,
                        const float* __restrict__ Wv, const float* __restrict__ Wo,
                        bf16_t* __restrict__ Qf, bf16_t* __restrict__ Kf,
                        bf16_t* __restrict__ Vf, bf16_t* __restrict__ WoF) {
    const int b = blockIdx.x;
    const int s  = (b & 7) * 16 + ((b >> 3) & 15);  // XCD swizzle: xcd -> 16-s band
    const int sl = b >> 7;                          // 0..23
    const int h  = sl & 7;
    const int which = sl >> 3;                      // 0=Q 1=K 2=V
    const int tid = threadIdx.x, lane = tid & 63, w = tid >> 6;
    const int quad = lane >> 4, l16 = lane & 15;
    const f32x4 vzero = {0.f, 0.f, 0.f, 0.f};

    __shared__ __attribute__((aligned(16))) bf16_t sWT[DH][CIN + 8];  // [d][k] 4.6 KB
    __shared__ __attribute__((aligned(16))) bf16_t sT[4][32][40];     // 10.2 KB
    __shared__ __attribute__((aligned(16))) bf16_t sWoT[CIN][40];     // 5 KB (special only)

    const float* __restrict__ X = (which == 0) ? Xq : Xkv;
    const float* __restrict__ W = (which == 0) ? Wq : (which == 1 ? Wk : Wv);
    const float scale = (which == 0) ? 0.17677669529663687f : 1.0f;  // 1/sqrt(32)
    const bool special = (which == 1) && (s == 0) && (WoF != nullptr);

    // stage W^T head-slice: sWT[d][k], coalesced f32x4 (2 per thread)
#pragma unroll
    for (int it = 0; it < 2; ++it) {
        const int idx = it * 256 + tid;
        const int k = idx >> 3, c4 = (idx & 7) << 2;
        const f32x4 w4 = *(const f32x4*)&W[k * HD + h * DH + c4];
#pragma unroll
        for (int j = 0; j < 4; ++j) sWT[c4 + j][k] = f2bf(w4[j]);
    }
    if (special) {
        // stage Wo^T head-slice: sWoT[n=cq][k=d], 2 f32x4 per thread
#pragma unroll
        for (int it = 0; it < 2; ++it) {
            const int idx = it * 256 + tid;
            const int kk = idx >> 4, c4 = (idx & 15) << 2;
            const f32x4 w4 = *(const f32x4*)&Wo[(h * DH + kk) * CIN + c4];
#pragma unroll
            for (int j = 0; j < 4; ++j) sWoT[c4 + j][kk] = f2bf(w4[j]);
        }
    }
    __syncthreads();

    if (special) {
        // WoF frag: B[k=d=quad*8+j][n=w*16+l16] (wave w emits n-tile w)
        const bf16x8 f = *(const bf16x8*)&sWoT[w * 16 + l16][quad * 8];
        *(bf16x8*)&WoF[(size_t)(h * 4 + w) * 512 + lane * 8] = f;
    }

    // weight B-frags: B[k=ks*32+quad*8+j][n=nt*16+l16]
    bf16x8 bw[2][2];
#pragma unroll
    for (int nt = 0; nt < 2; ++nt)
#pragma unroll
        for (int ks = 0; ks < 2; ++ks)
            bw[nt][ks] = *(const bf16x8*)&sWT[nt * 16 + l16][ks * 32 + quad * 8];

    const size_t base = (size_t)(s * NH + h) * 8192;

    if (which < 2) {
        bf16_t* __restrict__ Dst = which ? Kf : Qf;
#pragma unroll 1
        for (int t = 0; t < 4; ++t) {
            const int mt = t * 4 + w;  // wave w owns tiles {w, w+4, w+8, w+12}
            const float* xp = &X[(s * QL + mt * 16 + l16) * CIN + quad * 8];
            const bf16x8 a0 = cvt8(xp);
            const bf16x8 a1 = cvt8(xp + 32);
            f32x4 c0 = vzero, c1 = vzero;
            c0 = mfma16(a0, bw[0][0], c0);
            c0 = mfma16(a1, bw[0][1], c0);
            c1 = mfma16(a0, bw[1][0], c1);
            c1 = mfma16(a1, bw[1][1], c1);
            // C/D (row=quad*4+r, d=nt*16+l16) -> sT -> frag (same-wave RT)
#pragma unroll
            for (int nt = 0; nt < 2; ++nt) {
                const f32x4 c = nt ? c1 : c0;
#pragma unroll
                for (int r = 0; r < 4; ++r)
                    sT[w][quad * 4 + r][nt * 16 + l16] = f2bf(c[r] * scale);
            }
            const bf16x8 frag = *(const bf16x8*)&sT[w][l16][quad * 8];
            *(bf16x8*)&Dst[base + (size_t)mt * 512 + lane * 8] = frag;
        }
    } else {
#pragma unroll 1
        for (int ch = 0; ch < 2; ++ch) {
            const int cs = ch * 4 + w;  // 32-kv chunk; wave w owns {w, w+4}
            bf16x8 a[2][2];
#pragma unroll
            for (int u = 0; u < 2; ++u) {
                const float* xp = &Xkv[(s * KL + cs * 32 + u * 16 + l16) * CIN + quad * 8];
                a[u][0] = cvt8(xp);
                a[u][1] = cvt8(xp + 32);
            }
            // C/D (kv=u*16+quad*4+r, d=nth*16+l16) -> sT[d][kv] (transposed)
#pragma unroll
            for (int u = 0; u < 2; ++u)
#pragma unroll
                for (int nth = 0; nth < 2; ++nth) {
                    f32x4 c = mfma16(a[u][0], bw[nth][0], vzero);
                    c = mfma16(a[u][1], bw[nth][1], c);
#pragma unroll
                    for (int r = 0; r < 4; ++r)
                        sT[w][nth * 16 + l16][u * 16 + quad * 4 + r] = f2bf(c[r]);
                }
#pragma unroll
            for (int nt = 0; nt < 2; ++nt) {
                const bf16x8 frag = *(const bf16x8*)&sT[w][nt * 16 + l16][quad * 8];
                *(bf16x8*)&Vf[base + (size_t)(cs * 2 + nt) * 512 + lane * 8] = frag;
            }
        }
    }
}

// ---------------------------------------------------------------------------
// Phase 2: attention, barrier-free pure consumer (r7 structure, proven:
// FETCH 33 MB). Only change: 8 blocks/CU for latency hiding.
__launch_bounds__(256, 8)
__global__ void attn3(const float* __restrict__ Mask, const float* __restrict__ Bias,
                      const bf16_t* __restrict__ Qf, const bf16_t* __restrict__ Kf,
                      const bf16_t* __restrict__ Vf, bf16_t* __restrict__ Ows) {
    const int s = blockIdx.x, qt = blockIdx.y, h = blockIdx.z;
    const int tid = threadIdx.x, lane = tid & 63, w = tid >> 6;
    const int quad = lane >> 4, l16 = lane & 15;
    const f32x4 vzero = {0.f, 0.f, 0.f, 0.f};

    __shared__ __attribute__((aligned(16))) bf16_t sPT[4][16][72];  // 9.2 KB

    const int tile = qt * 4 + w, q0 = tile * 16;
    const size_t base = (size_t)(s * NH + h) * 8192;

    const bf16x8 qfr = *(const bf16x8*)&Qf[base + (size_t)tile * 512 + lane * 8];

    // S' = K·Q^T: C/D row=kv-local (quad*4+r), col=q (l16)
    f32x4 sv[16];
#pragma unroll
    for (int ct = 0; ct < 16; ++ct) {
        const bf16x8 ak = *(const bf16x8*)&Kf[base + ct * 512 + lane * 8];
        sv[ct] = mfma16(ak, qfr, vzero);
    }
    const float* bbase = &Bias[(size_t)(h * QL + q0 + l16) * KL];
    const float* mbase = &Mask[s * KL];
#pragma unroll
    for (int ct = 0; ct < 16; ++ct) {
        const f32x4 b4 = *(const f32x4*)&bbase[ct * 16 + quad * 4];
        const f32x4 m4 = *(const f32x4*)&mbase[ct * 16 + quad * 4];
        sv[ct] = sv[ct] + b4 + (m4 - 1.0f) * 1.0e9f;
    }
    // softmax over kv: per-lane 64 values + xor 16/32 across quads
    float mx = -1e30f;
#pragma unroll
    for (int ct = 0; ct < 16; ++ct)
#pragma unroll
        for (int r = 0; r < 4; ++r) mx = fmaxf(mx, sv[ct][r]);
    mx = fmaxf(mx, __shfl_xor(mx, 16, 64));
    mx = fmaxf(mx, __shfl_xor(mx, 32, 64));
    float sum = 0.f;
#pragma unroll
    for (int ct = 0; ct < 16; ++ct)
#pragma unroll
        for (int r = 0; r < 4; ++r) {
            const float e = __expf(sv[ct][r] - mx);
            sv[ct][r] = e;
            sum += e;
        }
    sum += __shfl_xor(sum, 16, 64);
    sum += __shfl_xor(sum, 32, 64);
    const float rs = 1.0f / sum;

    // PV in four 64-kv chunks: normalized P^T -> sPT -> A-frags; V from ws
    f32x4 o0 = vzero, o1 = vzero;
#pragma unroll
    for (int c = 0; c < 4; ++c) {
#pragma unroll
        for (int cc = 0; cc < 4; ++cc) {
            const int ct = c * 4 + cc;
            bf16x4_t pv;
#pragma unroll
            for (int r = 0; r < 4; ++r) pv[r] = f2bf(sv[ct][r] * rs);
            *(bf16x4_t*)&sPT[w][l16][cc * 16 + quad * 4] = pv;
        }
#pragma unroll
        for (int ks = 0; ks < 2; ++ks) {
            const bf16x8 ap  = *(const bf16x8*)&sPT[w][l16][ks * 32 + quad * 8];
            const bf16x8 bv0 = *(const bf16x8*)&Vf[base + ((c * 2 + ks) * 2 + 0) * 512 + lane * 8];
            const bf16x8 bv1 = *(const bf16x8*)&Vf[base + ((c * 2 + ks) * 2 + 1) * 512 + lane * 8];
            o0 = mfma16(ap, bv0, o0);
            o1 = mfma16(ap, bv1, o1);
        }
    }
    // O tile (q=quad*4+r, d=nt*16+l16) -> Ows[s][h][tile][q][d] (aliases Qf;
    // qfr consumed above -> read-before-write within the wave)
    bf16_t* dst = &Ows[base + (size_t)tile * 512];
#pragma unroll
    for (int nt = 0; nt < 2; ++nt) {
        const f32x4 o = nt ? o1 : o0;
#pragma unroll
        for (int r = 0; r < 4; ++r)
            dst[(quad * 4 + r) * DH + nt * 16 + l16] = f2bf(o[r]);
    }
}

// ---------------------------------------------------------------------------
// Phase 3 v3: barrier-free outproj consuming fragment-native WoF.
// 2048 one-wave blocks (one 16-row m-tile each): 8 a-frags + 32 WoF frags
// (L2 broadcast) + 32 MFMA + 16 stores. No LDS, no barrier.
__launch_bounds__(64, 4)
__global__ void outproj3(const bf16_t* __restrict__ Ows, const bf16_t* __restrict__ WoF,
                         const float* __restrict__ Bo, float* __restrict__ Out) {
    const int b = blockIdx.x;                 // m-tile index, 0..2047
    const int s = b >> 4, tile = b & 15;
    const int lane = threadIdx.x & 63;
    const int quad = lane >> 4, l16 = lane & 15;
    const f32x4 vzero = {0.f, 0.f, 0.f, 0.f};

    f32x4 acc[4];
#pragma unroll
    for (int nt = 0; nt < 4; ++nt) acc[nt] = vzero;
#pragma unroll
    for (int h = 0; h < NH; ++h) {
        // A[m=q=l16][k=d=quad*8+j] from frag-native Ows
        const bf16x8 a = *(const bf16x8*)&Ows[((size_t)(s * NH + h) * 16 + tile) * 512 +
                                              l16 * DH + quad * 8];
#pragma unroll
        for (int nt = 0; nt < 4; ++nt) {
            const bf16x8 bwo = *(const bf16x8*)&WoF[(size_t)(h * 4 + nt) * 512 + lane * 8];
            acc[nt] = mfma16(a, bwo, acc[nt]);
        }
    }
    const int mr0 = b * 16;
#pragma unroll
    for (int nt = 0; nt < 4; ++nt) {
        const float bo = Bo[nt * 16 + l16];
#pragma unroll
        for (int r = 0; r < 4; ++r)
            Out[(mr0 + quad * 4 + r) * CIN + nt * 16 + l16] = acc[nt][r] + bo;
    }
}

// ---------------------------------------------------------------------------
// Phase 3 fallback (r7-proven): staged Wo, used only if ws lacks WoF room.
__launch_bounds__(256, 4)
__global__ void outproj2(const bf16_t* __restrict__ Ows, const float* __restrict__ Wo,
                         const float* __restrict__ Bo, float* __restrict__ Out) {
    const int tid = threadIdx.x, lane = tid & 63, w = tid >> 6;
    const int quad = lane >> 4, l16 = lane & 15;
    const int R = blockIdx.x * 128;
    const int s = R >> 8;

    __shared__ __attribute__((aligned(16))) bf16_t sWoT[CIN][HD + 8];
    __shared__ float sBo[CIN];

#pragma unroll
    for (int it = 0; it < 16; ++it) {
        const int idx = it * 256 + tid;
        const int kk = idx >> 4, c4 = (idx & 15) << 2;
        const f32x4 w4 = *(const f32x4*)&Wo[kk * CIN + c4];
#pragma unroll
        for (int j = 0; j < 4; ++j) sWoT[c4 + j][kk] = f2bf(w4[j]);
    }
    if (tid < CIN) sBo[tid] = Bo[tid];
    __syncthreads();

    const f32x4 vzero = {0.f, 0.f, 0.f, 0.f};
#pragma unroll 1
    for (int i = 0; i < 2; ++i) {
        const int mr0 = R + w * 32 + i * 16;
        const int tile = (mr0 & 255) >> 4;
        bf16x8 a[8];
#pragma unroll
        for (int ks = 0; ks < 8; ++ks)
            a[ks] = *(const bf16x8*)&Ows[((size_t)(s * NH + ks) * 16 + tile) * 512 +
                                         l16 * DH + quad * 8];
        f32x4 acc[4];
#pragma unroll
        for (int nt = 0; nt < 4; ++nt) acc[nt] = vzero;
#pragma unroll
        for (int ks = 0; ks < 8; ++ks)
#pragma unroll
            for (int nt = 0; nt < 4; ++nt) {
                const bf16x8 bb = *(const bf16x8*)&sWoT[nt * 16 + l16][ks * 32 + quad * 8];
                acc[nt] = mfma16(a[ks], bb, acc[nt]);
            }
#pragma unroll
        for (int nt = 0; nt < 4; ++nt) {
            const float bo = sBo[nt * 16 + l16];
#pragma unroll
            for (int r = 0; r < 4; ++r)
                Out[(mr0 + quad * 4 + r) * CIN + nt * 16 + l16] = acc[nt][r] + bo;
        }
    }
}

extern "C" void kernel_launch(void* const* d_in, const int* in_sizes, int n_in,
                              void* d_out, int out_size, void* d_ws, size_t ws_size,
                              hipStream_t stream) {
    const float* Xq   = (const float*)d_in[0];
    const float* Xkv  = (const float*)d_in[1];
    const float* Mask = (const float*)d_in[2];
    const float* Bias = (const float*)d_in[3];
    const float* Wq   = (const float*)d_in[4];
    const float* Wk   = (const float*)d_in[5];
    const float* Wv   = (const float*)d_in[6];
    const float* Wo   = (const float*)d_in[7];
    const float* Bo   = (const float*)d_in[8];
    float* Out = (float*)d_out;

    const size_t SEG = 16777216;  // 16 MiB; ws >= 48 MiB proven in r5-r7
    bf16_t* Qf  = (bf16_t*)d_ws;
    bf16_t* Kf  = (bf16_t*)((char*)d_ws + SEG);
    bf16_t* Vf  = (bf16_t*)((char*)d_ws + 2 * SEG);
    bf16_t* Ows = Qf;  // aliased: per-(s,h,tile) read-before-write within one wave
    const bool haveWoF = ws_size >= 3 * SEG + 32768;
    bf16_t* WoF = haveWoF ? (bf16_t*)((char*)d_ws + 3 * SEG) : nullptr;

    proj_v2<<<3072, 256, 0, stream>>>(Xq, Xkv, Wq, Wk, Wv, Wo, Qf, Kf, Vf, WoF);
    attn3<<<dim3(128, 4, NH), 256, 0, stream>>>(Mask, Bias, Qf, Kf, Vf, Ows);
    if (haveWoF)
        outproj3<<<2048, 64, 0, stream>>>(Ows, WoF, Bo, Out);
    else
        outproj2<<<256, 256, 0, stream>>>(Ows, Wo, Bo, Out);
}

// Round 9
// 165.979 us; speedup vs baseline: 1.8611x; 1.8611x over previous
//
#include <hip/hip_runtime.h>

typedef __bf16 bf16_t;
typedef __bf16 bf16x4_t __attribute__((ext_vector_type(4)));
typedef __bf16 bf16x8 __attribute__((ext_vector_type(8)));
typedef float f32x4 __attribute__((ext_vector_type(4)));

#define NH 8
#define DH 32
#define QL 256
#define KL 256
#define CIN 64
#define HD 256  // NH*DH

__device__ __forceinline__ bf16_t f2bf(float x) { return (bf16_t)x; }

__device__ __forceinline__ f32x4 mfma16(bf16x8 a, bf16x8 b, f32x4 c) {
    return __builtin_amdgcn_mfma_f32_16x16x32_bf16(a, b, c, 0, 0, 0);
}

__device__ __forceinline__ bf16x8 cvt8(const float* __restrict__ p) {
    const f32x4 lo = *(const f32x4*)p;
    const f32x4 hi = *(const f32x4*)(p + 4);
    bf16x8 r;
#pragma unroll
    for (int j = 0; j < 4; ++j) { r[j] = f2bf(lo[j]); r[4 + j] = f2bf(hi[j]); }
    return r;
}

// ---------------------------------------------------------------------------
// Phase 1: high-TLP projection, 2-wide ILP. Flat grid 3072 = (s, h, which),
// XCD swizzle (b&7 -> 16-s band, L2-resident X). 4 blocks/CU (128-VGPR
// budget, no spill — r8 lesson: tighter bounds spill and cost 10x in traffic).
__launch_bounds__(256, 4)
__global__ void proj_v2(const float* __restrict__ Xq, const float* __restrict__ Xkv,
                        const float* __restrict__ Wq, const float* __restrict__ Wk,
                        const float* __restrict__ Wv, const float* __restrict__ Wo,
                        bf16_t* __restrict__ Qf, bf16_t* __restrict__ Kf,
                        bf16_t* __restrict__ Vf, bf16_t* __restrict__ WoF) {
    const int b = blockIdx.x;
    const int s  = (b & 7) * 16 + ((b >> 3) & 15);  // XCD swizzle
    const int sl = b >> 7;
    const int h  = sl & 7;
    const int which = sl >> 3;                      // 0=Q 1=K 2=V
    const int tid = threadIdx.x, lane = tid & 63, w = tid >> 6;
    const int quad = lane >> 4, l16 = lane & 15;
    const f32x4 vzero = {0.f, 0.f, 0.f, 0.f};

    __shared__ __attribute__((aligned(16))) bf16_t sWT[DH][CIN + 8];   // 4.6 KB
    __shared__ __attribute__((aligned(16))) bf16_t sT[4][2][32][40];   // 20.5 KB (2-wide ILP)
    __shared__ __attribute__((aligned(16))) bf16_t sWoT[CIN][40];      // 5 KB

    const float* __restrict__ X = (which == 0) ? Xq : Xkv;
    const float* __restrict__ W = (which == 0) ? Wq : (which == 1 ? Wk : Wv);
    const float scale = (which == 0) ? 0.17677669529663687f : 1.0f;  // 1/sqrt(32)
    const bool special = (which == 1) && (s == 0) && (WoF != nullptr);

    // stage W^T head-slice: sWT[d][k], coalesced f32x4
#pragma unroll
    for (int it = 0; it < 2; ++it) {
        const int idx = it * 256 + tid;
        const int k = idx >> 3, c4 = (idx & 7) << 2;
        const f32x4 w4 = *(const f32x4*)&W[k * HD + h * DH + c4];
#pragma unroll
        for (int j = 0; j < 4; ++j) sWT[c4 + j][k] = f2bf(w4[j]);
    }
    if (special) {
#pragma unroll
        for (int it = 0; it < 2; ++it) {
            const int idx = it * 256 + tid;
            const int kk = idx >> 4, c4 = (idx & 15) << 2;
            const f32x4 w4 = *(const f32x4*)&Wo[(h * DH + kk) * CIN + c4];
#pragma unroll
            for (int j = 0; j < 4; ++j) sWoT[c4 + j][kk] = f2bf(w4[j]);
        }
    }
    __syncthreads();

    if (special) {
        const bf16x8 f = *(const bf16x8*)&sWoT[w * 16 + l16][quad * 8];
        *(bf16x8*)&WoF[(size_t)(h * 4 + w) * 512 + lane * 8] = f;
    }

    // weight B-frags: B[k=ks*32+quad*8+j][n=nt*16+l16]
    bf16x8 bw[2][2];
#pragma unroll
    for (int nt = 0; nt < 2; ++nt)
#pragma unroll
        for (int ks = 0; ks < 2; ++ks)
            bw[nt][ks] = *(const bf16x8*)&sWT[nt * 16 + l16][ks * 32 + quad * 8];

    const size_t base = (size_t)(s * NH + h) * 8192;

    if (which < 2) {
        bf16_t* __restrict__ Dst = which ? Kf : Qf;
#pragma unroll 1
        for (int tp = 0; tp < 2; ++tp) {
            // two independent tiles in flight (ILP): mtA, mtB
            const int mtA = tp * 8 + w, mtB = tp * 8 + w + 4;
            const float* xpA = &X[(s * QL + mtA * 16 + l16) * CIN + quad * 8];
            const float* xpB = &X[(s * QL + mtB * 16 + l16) * CIN + quad * 8];
            const bf16x8 aA0 = cvt8(xpA), aA1 = cvt8(xpA + 32);
            const bf16x8 aB0 = cvt8(xpB), aB1 = cvt8(xpB + 32);
            f32x4 cA0 = vzero, cA1 = vzero, cB0 = vzero, cB1 = vzero;
            cA0 = mfma16(aA0, bw[0][0], cA0);
            cB0 = mfma16(aB0, bw[0][0], cB0);
            cA0 = mfma16(aA1, bw[0][1], cA0);
            cB0 = mfma16(aB1, bw[0][1], cB0);
            cA1 = mfma16(aA0, bw[1][0], cA1);
            cB1 = mfma16(aB0, bw[1][0], cB1);
            cA1 = mfma16(aA1, bw[1][1], cA1);
            cB1 = mfma16(aB1, bw[1][1], cB1);
            // C/D (row=quad*4+r, d=nt*16+l16) -> sT -> frag (same-wave RT)
#pragma unroll
            for (int nt = 0; nt < 2; ++nt) {
                const f32x4 cA = nt ? cA1 : cA0;
                const f32x4 cB = nt ? cB1 : cB0;
#pragma unroll
                for (int r = 0; r < 4; ++r) {
                    sT[w][0][quad * 4 + r][nt * 16 + l16] = f2bf(cA[r] * scale);
                    sT[w][1][quad * 4 + r][nt * 16 + l16] = f2bf(cB[r] * scale);
                }
            }
            const bf16x8 fragA = *(const bf16x8*)&sT[w][0][l16][quad * 8];
            const bf16x8 fragB = *(const bf16x8*)&sT[w][1][l16][quad * 8];
            *(bf16x8*)&Dst[base + (size_t)mtA * 512 + lane * 8] = fragA;
            *(bf16x8*)&Dst[base + (size_t)mtB * 512 + lane * 8] = fragB;
        }
    } else {
        // two independent 32-kv chunks in flight: csA = w, csB = w+4
        const int csA = w, csB = w + 4;
        bf16x8 aA[2][2], aB[2][2];
#pragma unroll
        for (int u = 0; u < 2; ++u) {
            const float* xpA = &Xkv[(s * KL + csA * 32 + u * 16 + l16) * CIN + quad * 8];
            const float* xpB = &Xkv[(s * KL + csB * 32 + u * 16 + l16) * CIN + quad * 8];
            aA[u][0] = cvt8(xpA); aA[u][1] = cvt8(xpA + 32);
            aB[u][0] = cvt8(xpB); aB[u][1] = cvt8(xpB + 32);
        }
        // C/D (kv=u*16+quad*4+r, d=nth*16+l16) -> sT[d][kv] (transposed)
#pragma unroll
        for (int u = 0; u < 2; ++u)
#pragma unroll
            for (int nth = 0; nth < 2; ++nth) {
                f32x4 cA = mfma16(aA[u][0], bw[nth][0], vzero);
                f32x4 cB = mfma16(aB[u][0], bw[nth][0], vzero);
                cA = mfma16(aA[u][1], bw[nth][1], cA);
                cB = mfma16(aB[u][1], bw[nth][1], cB);
#pragma unroll
                for (int r = 0; r < 4; ++r) {
                    sT[w][0][nth * 16 + l16][u * 16 + quad * 4 + r] = f2bf(cA[r]);
                    sT[w][1][nth * 16 + l16][u * 16 + quad * 4 + r] = f2bf(cB[r]);
                }
            }
#pragma unroll
        for (int nt = 0; nt < 2; ++nt) {
            const bf16x8 fA = *(const bf16x8*)&sT[w][0][nt * 16 + l16][quad * 8];
            const bf16x8 fB = *(const bf16x8*)&sT[w][1][nt * 16 + l16][quad * 8];
            *(bf16x8*)&Vf[base + (size_t)(csA * 2 + nt) * 512 + lane * 8] = fA;
            *(bf16x8*)&Vf[base + (size_t)(csB * 2 + nt) * 512 + lane * 8] = fB;
        }
    }
}

// ---------------------------------------------------------------------------
// Phase 2: attention, barrier-free pure consumer. r7-proven config:
// 4 blocks/CU (NOT 8 — r8 showed the 32-VGPR squeeze spills sv[16] to
// scratch: WRITE 16->536 MB). PV now in two 128-kv chunks (2 LDS RTs, was 4).
__launch_bounds__(256, 4)
__global__ void attn3(const float* __restrict__ Mask, const float* __restrict__ Bias,
                      const bf16_t* __restrict__ Qf, const bf16_t* __restrict__ Kf,
                      const bf16_t* __restrict__ Vf, bf16_t* __restrict__ Ows) {
    const int s = blockIdx.x, qt = blockIdx.y, h = blockIdx.z;
    const int tid = threadIdx.x, lane = tid & 63, w = tid >> 6;
    const int quad = lane >> 4, l16 = lane & 15;
    const f32x4 vzero = {0.f, 0.f, 0.f, 0.f};

    __shared__ __attribute__((aligned(16))) bf16_t sPT[4][16][136];  // 17.4 KB

    const int tile = qt * 4 + w, q0 = tile * 16;
    const size_t base = (size_t)(s * NH + h) * 8192;

    const bf16x8 qfr = *(const bf16x8*)&Qf[base + (size_t)tile * 512 + lane * 8];

    // S' = K·Q^T: C/D row=kv-local (quad*4+r), col=q (l16)
    f32x4 sv[16];
#pragma unroll
    for (int ct = 0; ct < 16; ++ct) {
        const bf16x8 ak = *(const bf16x8*)&Kf[base + ct * 512 + lane * 8];
        sv[ct] = mfma16(ak, qfr, vzero);
    }
    const float* bbase = &Bias[(size_t)(h * QL + q0 + l16) * KL];
    const float* mbase = &Mask[s * KL];
#pragma unroll
    for (int ct = 0; ct < 16; ++ct) {
        const f32x4 b4 = *(const f32x4*)&bbase[ct * 16 + quad * 4];
        const f32x4 m4 = *(const f32x4*)&mbase[ct * 16 + quad * 4];
        sv[ct] = sv[ct] + b4 + (m4 - 1.0f) * 1.0e9f;
    }
    // softmax over kv: per-lane 64 values + xor 16/32 across quads
    float mx = -1e30f;
#pragma unroll
    for (int ct = 0; ct < 16; ++ct)
#pragma unroll
        for (int r = 0; r < 4; ++r) mx = fmaxf(mx, sv[ct][r]);
    mx = fmaxf(mx, __shfl_xor(mx, 16, 64));
    mx = fmaxf(mx, __shfl_xor(mx, 32, 64));
    float sum = 0.f;
#pragma unroll
    for (int ct = 0; ct < 16; ++ct)
#pragma unroll
        for (int r = 0; r < 4; ++r) {
            const float e = __expf(sv[ct][r] - mx);
            sv[ct][r] = e;
            sum += e;
        }
    sum += __shfl_xor(sum, 16, 64);
    sum += __shfl_xor(sum, 32, 64);
    const float rs = 1.0f / sum;

    // PV in two 128-kv chunks: normalized P^T -> sPT -> A-frags; V from ws
    f32x4 o0 = vzero, o1 = vzero;
#pragma unroll
    for (int c = 0; c < 2; ++c) {
#pragma unroll
        for (int cc = 0; cc < 8; ++cc) {
            const int ct = c * 8 + cc;
            bf16x4_t pv;
#pragma unroll
            for (int r = 0; r < 4; ++r) pv[r] = f2bf(sv[ct][r] * rs);
            *(bf16x4_t*)&sPT[w][l16][cc * 16 + quad * 4] = pv;
        }
#pragma unroll
        for (int ks = 0; ks < 4; ++ks) {
            const bf16x8 ap = *(const bf16x8*)&sPT[w][l16][ks * 32 + quad * 8];
            const int cs = c * 4 + ks;
            const bf16x8 bv0 = *(const bf16x8*)&Vf[base + (size_t)(cs * 2 + 0) * 512 + lane * 8];
            const bf16x8 bv1 = *(const bf16x8*)&Vf[base + (size_t)(cs * 2 + 1) * 512 + lane * 8];
            o0 = mfma16(ap, bv0, o0);
            o1 = mfma16(ap, bv1, o1);
        }
    }
    // O tile (q=quad*4+r, d=nt*16+l16) -> Ows[s][h][tile][q][d] (aliases Qf;
    // qfr consumed above -> read-before-write within the wave)
    bf16_t* dst = &Ows[base + (size_t)tile * 512];
#pragma unroll
    for (int nt = 0; nt < 2; ++nt) {
        const f32x4 o = nt ? o1 : o0;
#pragma unroll
        for (int r = 0; r < 4; ++r)
            dst[(quad * 4 + r) * DH + nt * 16 + l16] = f2bf(o[r]);
    }
}

// ---------------------------------------------------------------------------
// Phase 3: barrier-free outproj consuming fragment-native WoF.
// 2048 one-wave blocks: 8 a-frags + 32 WoF frags (L2 broadcast) + 32 MFMA.
__launch_bounds__(64, 4)
__global__ void outproj3(const bf16_t* __restrict__ Ows, const bf16_t* __restrict__ WoF,
                         const float* __restrict__ Bo, float* __restrict__ Out) {
    const int b = blockIdx.x;                 // m-tile index, 0..2047
    const int s = b >> 4, tile = b & 15;
    const int lane = threadIdx.x & 63;
    const int quad = lane >> 4, l16 = lane & 15;
    const f32x4 vzero = {0.f, 0.f, 0.f, 0.f};

    f32x4 acc[4];
#pragma unroll
    for (int nt = 0; nt < 4; ++nt) acc[nt] = vzero;
#pragma unroll
    for (int h = 0; h < NH; ++h) {
        const bf16x8 a = *(const bf16x8*)&Ows[((size_t)(s * NH + h) * 16 + tile) * 512 +
                                              l16 * DH + quad * 8];
#pragma unroll
        for (int nt = 0; nt < 4; ++nt) {
            const bf16x8 bwo = *(const bf16x8*)&WoF[(size_t)(h * 4 + nt) * 512 + lane * 8];
            acc[nt] = mfma16(a, bwo, acc[nt]);
        }
    }
    const int mr0 = b * 16;
#pragma unroll
    for (int nt = 0; nt < 4; ++nt) {
        const float bo = Bo[nt * 16 + l16];
#pragma unroll
        for (int r = 0; r < 4; ++r)
            Out[(mr0 + quad * 4 + r) * CIN + nt * 16 + l16] = acc[nt][r] + bo;
    }
}

// ---------------------------------------------------------------------------
// Phase 3 fallback (r7-proven): staged Wo, used only if ws lacks WoF room.
__launch_bounds__(256, 4)
__global__ void outproj2(const bf16_t* __restrict__ Ows, const float* __restrict__ Wo,
                         const float* __restrict__ Bo, float* __restrict__ Out) {
    const int tid = threadIdx.x, lane = tid & 63, w = tid >> 6;
    const int quad = lane >> 4, l16 = lane & 15;
    const int R = blockIdx.x * 128;
    const int s = R >> 8;

    __shared__ __attribute__((aligned(16))) bf16_t sWoT[CIN][HD + 8];
    __shared__ float sBo[CIN];

#pragma unroll
    for (int it = 0; it < 16; ++it) {
        const int idx = it * 256 + tid;
        const int kk = idx >> 4, c4 = (idx & 15) << 2;
        const f32x4 w4 = *(const f32x4*)&Wo[kk * CIN + c4];
#pragma unroll
        for (int j = 0; j < 4; ++j) sWoT[c4 + j][kk] = f2bf(w4[j]);
    }
    if (tid < CIN) sBo[tid] = Bo[tid];
    __syncthreads();

    const f32x4 vzero = {0.f, 0.f, 0.f, 0.f};
#pragma unroll 1
    for (int i = 0; i < 2; ++i) {
        const int mr0 = R + w * 32 + i * 16;
        const int tile = (mr0 & 255) >> 4;
        bf16x8 a[8];
#pragma unroll
        for (int ks = 0; ks < 8; ++ks)
            a[ks] = *(const bf16x8*)&Ows[((size_t)(s * NH + ks) * 16 + tile) * 512 +
                                         l16 * DH + quad * 8];
        f32x4 acc[4];
#pragma unroll
        for (int nt = 0; nt < 4; ++nt) acc[nt] = vzero;
#pragma unroll
        for (int ks = 0; ks < 8; ++ks)
#pragma unroll
            for (int nt = 0; nt < 4; ++nt) {
                const bf16x8 bb = *(const bf16x8*)&sWoT[nt * 16 + l16][ks * 32 + quad * 8];
                acc[nt] = mfma16(a[ks], bb, acc[nt]);
            }
#pragma unroll
        for (int nt = 0; nt < 4; ++nt) {
            const float bo = sBo[nt * 16 + l16];
#pragma unroll
            for (int r = 0; r < 4; ++r)
                Out[(mr0 + quad * 4 + r) * CIN + nt * 16 + l16] = acc[nt][r] + bo;
        }
    }
}

extern "C" void kernel_launch(void* const* d_in, const int* in_sizes, int n_in,
                              void* d_out, int out_size, void* d_ws, size_t ws_size,
                              hipStream_t stream) {
    const float* Xq   = (const float*)d_in[0];
    const float* Xkv  = (const float*)d_in[1];
    const float* Mask = (const float*)d_in[2];
    const float* Bias = (const float*)d_in[3];
    const float* Wq   = (const float*)d_in[4];
    const float* Wk   = (const float*)d_in[5];
    const float* Wv   = (const float*)d_in[6];
    const float* Wo   = (const float*)d_in[7];
    const float* Bo   = (const float*)d_in[8];
    float* Out = (float*)d_out;

    const size_t SEG = 16777216;  // 16 MiB; ws >= 48 MiB proven in r5-r8
    bf16_t* Qf  = (bf16_t*)d_ws;
    bf16_t* Kf  = (bf16_t*)((char*)d_ws + SEG);
    bf16_t* Vf  = (bf16_t*)((char*)d_ws + 2 * SEG);
    bf16_t* Ows = Qf;  // aliased: per-(s,h,tile) read-before-write within one wave
    const bool haveWoF = ws_size >= 3 * SEG + 32768;
    bf16_t* WoF = haveWoF ? (bf16_t*)((char*)d_ws + 3 * SEG) : nullptr;

    proj_v2<<<3072, 256, 0, stream>>>(Xq, Xkv, Wq, Wk, Wv, Wo, Qf, Kf, Vf, WoF);
    attn3<<<dim3(128, 4, NH), 256, 0, stream>>>(Mask, Bias, Qf, Kf, Vf, Ows);
    if (haveWoF)
        outproj3<<<2048, 64, 0, stream>>>(Ows, WoF, Bo, Out);
    else
        outproj2<<<256, 256, 0, stream>>>(Ows, Wo, Bo, Out);
}